// Round 3
// baseline (647.679 us; speedup 1.0000x reference)
//
#include <hip/hip_runtime.h>
#include <math.h>

#define NPTS 4096
#define NB   8
#define NC   64
#define KSEL 30
#define NROWS (NB * NPTS * KSEL)   // 983040
#define CNT_F 983040.0f
#define NBLK  1024                 // coop grid: 4 blocks/CU on 256 CUs
#define GT    (NBLK * 256)         // 262144 threads

static __device__ __forceinline__ unsigned long long shfl_xor_u64(unsigned long long v, int lx) {
    int lo = __shfl_xor((int)(unsigned)(v & 0xFFFFFFFFULL), lx, 64);
    int hi = __shfl_xor((int)(unsigned)(v >> 32), lx, 64);
    return ((unsigned long long)(unsigned)hi << 32) | (unsigned)lo;
}

// ---------------------------------------------------------------------------
// Kernel 1: exact KNN + spherical features + BN1 sufficient statistics.
// 8 queries/block (one per wave). LDS: xyz 48KB + {xx-plane | survivors} 16KB.
// ---------------------------------------------------------------------------
__global__ __launch_bounds__(512, 4) void knn_k(const float* __restrict__ xloc,
                                                int* __restrict__ idx_out,
                                                float* __restrict__ sph,   // [3][NROWS]
                                                float* __restrict__ accM) {
    __shared__ float s3[NPTS * 3];   // 48KB: x,y,z interleaved per point
    __shared__ float swu[NPTS];      // 16KB: xx-plane, later surv(4KB)+moment scratch

    const int tid  = threadIdx.x;
    const int lane = tid & 63;
    const int wv   = tid >> 6;
    const int b    = blockIdx.y;
    const int n    = (blockIdx.x << 3) + wv;

    const float* xb = xloc + (size_t)b * (3 * NPTS);
    for (int i = tid; i < NPTS; i += 512) {
        const float x = xb[i], y = xb[NPTS + i], z = xb[2 * NPTS + i];
        s3[i * 3]     = x;
        s3[i * 3 + 1] = y;
        s3[i * 3 + 2] = z;
        swu[i] = __fadd_rn(__fadd_rn(__fmul_rn(x, x), __fmul_rn(y, y)), __fmul_rn(z, z));
    }
    __syncthreads();

    const float qx = s3[n * 3], qy = s3[n * 3 + 1], qz = s3[n * 3 + 2];
    const float qw = swu[n];

    // main loop: pd kept as float (no per-candidate key conversion)
    float P[64];
    float pmax = -3.4e38f;
#pragma unroll
    for (int t = 0; t < 64; ++t) {
        const int j = lane + (t << 6);
        const float cx = s3[j * 3], cy = s3[j * 3 + 1], cz = s3[j * 3 + 2];
        const float cw = swu[j];
        const float dt = __fadd_rn(__fadd_rn(__fmul_rn(qx, cx), __fmul_rn(qy, cy)), __fmul_rn(qz, cz));
        const float pd = __fsub_rn(__fsub_rn(__fadd_rn(dt, dt), qw), cw);
        P[t] = pd;
        pmax = fmaxf(pmax, pd);
    }

    // descending bitonic sort of 64 lane-maxima; tau = 31st largest
    float v = pmax;
#pragma unroll
    for (int k = 2; k <= 64; k <<= 1) {
#pragma unroll
        for (int j2 = k >> 1; j2 > 0; j2 >>= 1) {
            const float o = __shfl_xor(v, j2, 64);
            const bool keepmax = ((lane & j2) == 0) == ((lane & k) == 0);
            v = keepmax ? fmaxf(v, o) : fminf(v, o);
        }
    }
    const float tau = __shfl(v, 30, 64);

    __syncthreads();  // all waves done with swu-as-xx -> reuse as surv

    unsigned long long* surv = ((unsigned long long*)swu) + (wv << 6);
    surv[lane] = 0ULL;

    unsigned total = 0;
#pragma unroll
    for (int t = 0; t < 64; ++t) {
        const bool p = (P[t] >= tau);
        const unsigned long long m = __ballot(p);
        if (p) {
            const unsigned pos = total + (unsigned)__popcll(m & ((1ULL << lane) - 1ULL));
            if (pos < 64u) {
                const unsigned u = __float_as_uint(P[t]);
                const unsigned key = u ^ ((unsigned)((int)u >> 31) | 0x80000000u);
                surv[pos] = ((unsigned long long)key << 32) | (unsigned)(~(lane + (t << 6)));
            }
        }
        total += (unsigned)__popcll(m);
    }
    __threadfence_block();

    const int bn = (b << 12) + n;
    const size_t obase = (size_t)bn * KSEL;
    int jn = 0;

    if (total <= 64u) {
        unsigned long long s = surv[lane];
#pragma unroll
        for (int k = 2; k <= 64; k <<= 1) {
#pragma unroll
            for (int j2 = k >> 1; j2 > 0; j2 >>= 1) {
                const unsigned long long o = shfl_xor_u64(s, j2);
                const bool keepmax = ((lane & j2) == 0) == ((lane & k) == 0);
                const unsigned long long mx = s > o ? s : o;
                const unsigned long long mn = s > o ? o : s;
                s = keepmax ? mx : mn;
            }
        }
        jn = (int)(~(unsigned)s) & (NPTS - 1);
        if (lane >= KSEL) jn = 0;
    } else {
        // rare exact fallback: bisection, recomputing pd from intact s3 (never touches P[])
        auto keyf = [&](int j) -> unsigned {
            const float cx = s3[j * 3], cy = s3[j * 3 + 1], cz = s3[j * 3 + 2];
            const float cw = __fadd_rn(__fadd_rn(__fmul_rn(cx, cx), __fmul_rn(cy, cy)), __fmul_rn(cz, cz));
            const float dt = __fadd_rn(__fadd_rn(__fmul_rn(qx, cx), __fmul_rn(qy, cy)), __fmul_rn(qz, cz));
            const float pd = __fsub_rn(__fsub_rn(__fadd_rn(dt, dt), qw), cw);
            const unsigned u = __float_as_uint(pd);
            return u ^ ((unsigned)((int)u >> 31) | 0x80000000u);
        };
        unsigned Pv = 0;
        for (int bit = 31; bit >= 0; --bit) {
            const unsigned cand = Pv | (1u << bit);
            int c = 0;
            for (int t = 0; t < 64; ++t) c += (keyf(lane + (t << 6)) >= cand) ? 1 : 0;
            for (int o = 32; o > 0; o >>= 1) c += __shfl_xor(c, o, 64);
            if (c >= KSEL) Pv = cand;
        }
        int* sj = (int*)surv;  // reuse own slice for index staging
        int emitted = 0;
        for (int t = 0; t < 64; ++t) {
            const bool g = keyf(lane + (t << 6)) > Pv;
            const unsigned long long m = __ballot(g);
            if (g) {
                const int pos = emitted + (int)__popcll(m & ((1ULL << lane) - 1ULL));
                if (pos < KSEL) sj[pos] = lane + (t << 6);
            }
            emitted += (int)__popcll(m);
        }
        for (int t = 0; t < 64; ++t) {
            const bool e_ = (keyf(lane + (t << 6)) == Pv);
            const unsigned long long m = __ballot(e_);
            const int before = (int)__popcll(m & ((1ULL << lane) - 1ULL));
            if (e_ && (emitted + before) < KSEL) sj[emitted + before] = lane + (t << 6);
            emitted += (int)__popcll(m);
        }
        __threadfence_block();
        if (lane < KSEL) jn = sj[lane];
    }

    // spherical features for the 30 selected neighbors (s3 intact in LDS)
    float s0 = 0.0f, s1 = 0.0f, s2 = 0.0f;
    if (lane < KSEL) {
        idx_out[obase + lane] = jn;
        const float cx = s3[jn * 3], cy = s3[jn * 3 + 1], cz = s3[jn * 3 + 2];
        const float xr = cx - qx, yr = cy - qy, zr = cz - qz;
        const float sxy2 = xr * xr + yr * yr;
        const float r2   = sxy2 + zr * zr;
        const float rho  = sqrtf(fmaxf(r2, 1e-20f));
        const float sxy  = sqrtf(fmaxf(sxy2, 1e-20f));
        const bool dr = r2 < 1e-20f;
        const bool dp = sxy2 < 1e-20f;
        const float theta = atan2f(dr ? 0.0f : zr, dr ? 1.0f : sxy);
        const float phi   = atan2f(dp ? 0.0f : yr, dp ? 1.0f : xr);
        sph[obase + lane]             = rho;
        sph[NROWS + obase + lane]     = theta;
        sph[2 * NROWS + obase + lane] = phi;
        s0 = rho; s1 = theta; s2 = phi;
    }

    // BN1 sufficient statistics: sum sph, sum sph_a*sph_b
    float mom[9] = {s0, s1, s2, s0 * s0, s0 * s1, s0 * s2, s1 * s1, s1 * s2, s2 * s2};
#pragma unroll
    for (int o = 32; o > 0; o >>= 1) {
#pragma unroll
        for (int m = 0; m < 9; ++m) mom[m] += __shfl_xor(mom[m], o, 64);
    }
    float* msc = swu + 1024;  // past the 4KB surv region
    if (lane == 0) {
#pragma unroll
        for (int m = 0; m < 9; ++m) msc[wv * 9 + m] = mom[m];
    }
    __syncthreads();
    if (tid < 9) {
        float t_ = 0.0f;
#pragma unroll
        for (int w = 0; w < 8; ++w) t_ += msc[w * 9 + tid];
        atomicAdd(&accM[tid * 64 + ((blockIdx.y * (NPTS / 8) + blockIdx.x) & 63)], t_);
    }
}

// ---------------------------------------------------------------------------
// Kernel 2: tiled transpose x [B,C,N] -> xT [B,N,C]
// ---------------------------------------------------------------------------
__global__ __launch_bounds__(256) void transpose_k(const float* __restrict__ x,
                                                   float* __restrict__ xT) {
    __shared__ float tile[64][65];
    const int b  = blockIdx.y;
    const int n0 = blockIdx.x << 6;
    const int tx = threadIdx.x & 63;
    const int ty = threadIdx.x >> 6;
    const float* xb = x + ((size_t)b << 18);
#pragma unroll
    for (int i = 0; i < 16; ++i) {
        const int c = (i << 2) + ty;
        tile[c][tx] = xb[((size_t)c << 12) + n0 + tx];
    }
    __syncthreads();
    float* ob = xT + ((size_t)b << 18);
#pragma unroll
    for (int i = 0; i < 16; ++i) {
        const int nl = (i << 2) + ty;
        ob[((size_t)(n0 + nl) << 6) + tx] = tile[tx][nl];
    }
}

// ---------------------------------------------------------------------------
// Kernel 3: persistent fused MLP/BN/softmax/gather kernel with device barrier.
// ---------------------------------------------------------------------------
__device__ __forceinline__ void grid_barrier(unsigned* cnt) {
    __syncthreads();
    if (threadIdx.x == 0) {
        __threadfence();
        const unsigned arrived =
            __hip_atomic_fetch_add(cnt, 1u, __ATOMIC_ACQ_REL, __HIP_MEMORY_SCOPE_AGENT) + 1u;
        if (arrived < (unsigned)NBLK) {
            unsigned spins = 0;
            while (__hip_atomic_load(cnt, __ATOMIC_ACQUIRE, __HIP_MEMORY_SCOPE_AGENT) < (unsigned)NBLK &&
                   ++spins < (1u << 22)) {
                __builtin_amdgcn_s_sleep(2);
            }
        }
    }
    __syncthreads();
    __threadfence();
}

__global__ __launch_bounds__(256, 4) void coop_k(const float* __restrict__ x,
                                                 const float* __restrict__ W1,
                                                 const float* __restrict__ g1,
                                                 const float* __restrict__ b1,
                                                 const float* __restrict__ W2,
                                                 const float* __restrict__ g2,
                                                 const float* __restrict__ b2,
                                                 const float* __restrict__ W3,
                                                 const float* __restrict__ g3,
                                                 const float* __restrict__ b3,
                                                 const float* __restrict__ sph,
                                                 float* __restrict__ att,
                                                 const int* __restrict__ idx,
                                                 const float* __restrict__ xT,
                                                 const float* __restrict__ accM,
                                                 float* __restrict__ acc2,
                                                 float* __restrict__ acc3,
                                                 unsigned* __restrict__ bar,
                                                 float* __restrict__ out) {
    __shared__ float ubuf[64 * 65];   // transpose tile / moment scratch / agg tile
    __shared__ float sSum[27];
    __shared__ float sPar[20];        // sc1[6] sh1[6] sc2[3] sh2[3] sc3 sh3

    const int tid  = threadIdx.x;
    const int lane = tid & 63;
    const int wv   = tid >> 6;
    const int gtid = blockIdx.x * 256 + tid;
    const float invN = 1.0f / CNT_F;

    // ---- phase T: transpose (first 512 blocks), runs before any barrier ----
    if (blockIdx.x < 512) {
        const int b  = blockIdx.x >> 6;
        const int n0 = (blockIdx.x & 63) << 6;
        float (*tile)[65] = (float(*)[65])ubuf;
        const float* xb = x + ((size_t)b << 18);
#pragma unroll
        for (int i = 0; i < 16; ++i) {
            const int c = (i << 2) + (tid >> 6);
            tile[c][tid & 63] = xb[((size_t)c << 12) + n0 + (tid & 63)];
        }
        __syncthreads();
        float* ob = (float*)xT + ((size_t)b << 18);
#pragma unroll
        for (int i = 0; i < 16; ++i) {
            const int nl = (i << 2) + (tid >> 6);
            ob[((size_t)(n0 + nl) << 6) + (tid & 63)] = tile[tid & 63][nl];
        }
        __syncthreads();
    }

    // ---- phase 1: BN1 params from knn moments; h1 moments -> acc2 ----
    if (tid < 64) {
        float pm[9];
#pragma unroll
        for (int m = 0; m < 9; ++m) pm[m] = accM[m * 64 + tid];
#pragma unroll
        for (int o = 32; o > 0; o >>= 1) {
#pragma unroll
            for (int m = 0; m < 9; ++m) pm[m] += __shfl_xor(pm[m], o, 64);
        }
        if (tid == 0) {
#pragma unroll
            for (int m = 0; m < 9; ++m) sSum[m] = pm[m];
        }
    }
    __syncthreads();
    if (tid < 6) {
        const float m0 = sSum[0] * invN, m1 = sSum[1] * invN, m2 = sSum[2] * invN;
        const float E00 = sSum[3] * invN, E01 = sSum[4] * invN, E02 = sSum[5] * invN;
        const float E11 = sSum[6] * invN, E12 = sSum[7] * invN, E22 = sSum[8] * invN;
        const float* w = W1 + tid * 6;
        const float third = (w[3] + w[4] + w[5]) * (1.0f / 3.0f);
        const float a0 = w[0] + w[3] - third;
        const float a1 = w[1] + w[4] - third;
        const float a2 = w[2] + w[5] - third;
        const float mu = a0 * m0 + a1 * m1 + a2 * m2;
        const float E2 = a0 * a0 * E00 + a1 * a1 * E11 + a2 * a2 * E22 +
                         2.0f * (a0 * a1 * E01 + a0 * a2 * E02 + a1 * a2 * E12);
        const float var = E2 - mu * mu;
        const float sc = g1[tid] / sqrtf(var + 1e-5f);
        sPar[tid] = sc;
        sPar[6 + tid] = b1[tid] - mu * sc;
    }
    __syncthreads();

    // load this thread's rows of sph (held in registers through all phases)
    const int nrow = (gtid < (NROWS - 3 * GT)) ? 4 : 3;
    float rs0[4], rs1[4], rs2[4];
#pragma unroll
    for (int s = 0; s < 4; ++s) {
        if (s < nrow) {
            const size_t r = (size_t)gtid + (size_t)s * GT;
            rs0[s] = sph[r];
            rs1[s] = sph[NROWS + r];
            rs2[s] = sph[2 * NROWS + r];
        } else { rs0[s] = 0.0f; rs1[s] = 0.0f; rs2[s] = 0.0f; }
    }

    {
        float m27[27];
#pragma unroll
        for (int m = 0; m < 27; ++m) m27[m] = 0.0f;
        for (int s = 0; s < nrow; ++s) {
            const float mean = (rs0[s] + rs1[s] + rs2[s]) * (1.0f / 3.0f);
            const float f[6] = {rs0[s], rs1[s], rs2[s], rs0[s] - mean, rs1[s] - mean, rs2[s] - mean};
            float h1[6];
#pragma unroll
            for (int c = 0; c < 6; ++c) {
                float a = 0.0f;
#pragma unroll
                for (int d = 0; d < 6; ++d) a = fmaf(W1[c * 6 + d], f[d], a);
                const float z = fmaf(a, sPar[c], sPar[6 + c]);
                h1[c] = z >= 0.0f ? z : 0.2f * z;
            }
            int q = 6;
#pragma unroll
            for (int a2 = 0; a2 < 6; ++a2) {
                m27[a2] += h1[a2];
#pragma unroll
                for (int b2 = a2; b2 < 6; ++b2) m27[q++] += h1[a2] * h1[b2];
            }
        }
#pragma unroll
        for (int o = 32; o > 0; o >>= 1) {
#pragma unroll
            for (int m = 0; m < 27; ++m) m27[m] += __shfl_xor(m27[m], o, 64);
        }
        __syncthreads();
        if (lane == 0) {
#pragma unroll
            for (int m = 0; m < 27; ++m) ubuf[wv * 27 + m] = m27[m];
        }
        __syncthreads();
        if (tid < 27) {
            const float v = ubuf[tid] + ubuf[27 + tid] + ubuf[54 + tid] + ubuf[81 + tid];
            atomicAdd(&acc2[tid * 64 + (blockIdx.x & 63)], v);
        }
    }
    grid_barrier(bar + 0);

    // ---- phase 2: BN2 params; h2 moments -> acc3 ----
    if (tid < 64) {
        float pm[27];
#pragma unroll
        for (int m = 0; m < 27; ++m) pm[m] = acc2[m * 64 + tid];
#pragma unroll
        for (int o = 32; o > 0; o >>= 1) {
#pragma unroll
            for (int m = 0; m < 27; ++m) pm[m] += __shfl_xor(pm[m], o, 64);
        }
        if (tid == 0) {
#pragma unroll
            for (int m = 0; m < 27; ++m) sSum[m] = pm[m];
        }
    }
    __syncthreads();
    if (tid < 3) {
        float Eh[6];
#pragma unroll
        for (int d = 0; d < 6; ++d) Eh[d] = sSum[d] * invN;
        float M[6][6];
        int q = 6;
#pragma unroll
        for (int a2 = 0; a2 < 6; ++a2)
#pragma unroll
            for (int b2 = a2; b2 < 6; ++b2) {
                const float v = sSum[q++] * invN;
                M[a2][b2] = v; M[b2][a2] = v;
            }
        const float* w = W2 + tid * 6;
        float mu = 0.0f;
#pragma unroll
        for (int d = 0; d < 6; ++d) mu += w[d] * Eh[d];
        float E2 = 0.0f;
#pragma unroll
        for (int a2 = 0; a2 < 6; ++a2)
#pragma unroll
            for (int b2 = 0; b2 < 6; ++b2) E2 += w[a2] * w[b2] * M[a2][b2];
        const float var = E2 - mu * mu;
        const float sc = g2[tid] / sqrtf(var + 1e-5f);
        sPar[12 + tid] = sc;
        sPar[15 + tid] = b2[tid] - mu * sc;
    }
    __syncthreads();

    {
        float m9[9];
#pragma unroll
        for (int m = 0; m < 9; ++m) m9[m] = 0.0f;
        for (int s = 0; s < nrow; ++s) {
            const float mean = (rs0[s] + rs1[s] + rs2[s]) * (1.0f / 3.0f);
            const float f[6] = {rs0[s], rs1[s], rs2[s], rs0[s] - mean, rs1[s] - mean, rs2[s] - mean};
            float h1[6];
#pragma unroll
            for (int c = 0; c < 6; ++c) {
                float a = 0.0f;
#pragma unroll
                for (int d = 0; d < 6; ++d) a = fmaf(W1[c * 6 + d], f[d], a);
                const float z = fmaf(a, sPar[c], sPar[6 + c]);
                h1[c] = z >= 0.0f ? z : 0.2f * z;
            }
            float h2[3];
#pragma unroll
            for (int c = 0; c < 3; ++c) {
                float a = 0.0f;
#pragma unroll
                for (int d = 0; d < 6; ++d) a = fmaf(W2[c * 6 + d], h1[d], a);
                const float z = fmaf(a, sPar[12 + c], sPar[15 + c]);
                h2[c] = z >= 0.0f ? z : 0.2f * z;
            }
            m9[0] += h2[0]; m9[1] += h2[1]; m9[2] += h2[2];
            m9[3] += h2[0] * h2[0]; m9[4] += h2[0] * h2[1]; m9[5] += h2[0] * h2[2];
            m9[6] += h2[1] * h2[1]; m9[7] += h2[1] * h2[2]; m9[8] += h2[2] * h2[2];
        }
#pragma unroll
        for (int o = 32; o > 0; o >>= 1) {
#pragma unroll
            for (int m = 0; m < 9; ++m) m9[m] += __shfl_xor(m9[m], o, 64);
        }
        __syncthreads();
        if (lane == 0) {
#pragma unroll
            for (int m = 0; m < 9; ++m) ubuf[wv * 9 + m] = m9[m];
        }
        __syncthreads();
        if (tid < 9) {
            const float v = ubuf[tid] + ubuf[9 + tid] + ubuf[18 + tid] + ubuf[27 + tid];
            atomicAdd(&acc3[tid * 64 + (blockIdx.x & 63)], v);
        }
    }
    grid_barrier(bar + 1);

    // ---- phase 3: BN3 params; att = lrelu(BN3(y3)) ----
    if (tid < 64) {
        float pm[9];
#pragma unroll
        for (int m = 0; m < 9; ++m) pm[m] = acc3[m * 64 + tid];
#pragma unroll
        for (int o = 32; o > 0; o >>= 1) {
#pragma unroll
            for (int m = 0; m < 9; ++m) pm[m] += __shfl_xor(pm[m], o, 64);
        }
        if (tid == 0) {
#pragma unroll
            for (int m = 0; m < 9; ++m) sSum[m] = pm[m];
        }
    }
    __syncthreads();
    if (tid == 0) {
        const float Eh0 = sSum[0] * invN, Eh1 = sSum[1] * invN, Eh2 = sSum[2] * invN;
        const float M00 = sSum[3] * invN, M01 = sSum[4] * invN, M02 = sSum[5] * invN;
        const float M11 = sSum[6] * invN, M12 = sSum[7] * invN, M22 = sSum[8] * invN;
        const float w0 = W3[0], w1 = W3[1], w2 = W3[2];
        const float mu = w0 * Eh0 + w1 * Eh1 + w2 * Eh2;
        const float E2 = w0 * w0 * M00 + w1 * w1 * M11 + w2 * w2 * M22 +
                         2.0f * (w0 * w1 * M01 + w0 * w2 * M02 + w1 * w2 * M12);
        const float var = E2 - mu * mu;
        const float sc = g3[0] / sqrtf(var + 1e-5f);
        sPar[18] = sc;
        sPar[19] = b3[0] - mu * sc;
    }
    __syncthreads();

    for (int s = 0; s < nrow; ++s) {
        const float mean = (rs0[s] + rs1[s] + rs2[s]) * (1.0f / 3.0f);
        const float f[6] = {rs0[s], rs1[s], rs2[s], rs0[s] - mean, rs1[s] - mean, rs2[s] - mean};
        float h1[6];
#pragma unroll
        for (int c = 0; c < 6; ++c) {
            float a = 0.0f;
#pragma unroll
            for (int d = 0; d < 6; ++d) a = fmaf(W1[c * 6 + d], f[d], a);
            const float z = fmaf(a, sPar[c], sPar[6 + c]);
            h1[c] = z >= 0.0f ? z : 0.2f * z;
        }
        float h2[3];
#pragma unroll
        for (int c = 0; c < 3; ++c) {
            float a = 0.0f;
#pragma unroll
            for (int d = 0; d < 6; ++d) a = fmaf(W2[c * 6 + d], h1[d], a);
            const float z = fmaf(a, sPar[12 + c], sPar[15 + c]);
            h2[c] = z >= 0.0f ? z : 0.2f * z;
        }
        float a = 0.0f;
#pragma unroll
        for (int d = 0; d < 3; ++d) a = fmaf(W3[d], h2[d], a);
        const float z = fmaf(a, sPar[18], sPar[19]);
        const float av = z >= 0.0f ? z : 0.2f * z;
        const size_t r = (size_t)gtid + (size_t)s * GT;
        __hip_atomic_store(att + r, av, __ATOMIC_RELAXED, __HIP_MEMORY_SCOPE_AGENT);
    }
    grid_barrier(bar + 2);

    // ---- phase 4: softmax over k, gather, residual out (LDS-tiled stores) ----
    {
        const int p0 = blockIdx.x << 5;        // 32 consecutive points per block
        const int b  = p0 >> 12;
        const int n0 = p0 & (NPTS - 1);
        float (*agg)[65] = (float(*)[65])ubuf;  // [32 pts][64 ch +1 pad]
        const float* xTb = xT + ((size_t)b << 18);

        for (int i = 0; i < 8; ++i) {
            const int pl = (wv << 3) + i;
            const int p  = p0 + pl;
            float a = -3.4e38f;
            int jn = 0;
            if (lane < KSEL) {
                a  = __hip_atomic_load(att + (size_t)p * KSEL + lane, __ATOMIC_RELAXED, __HIP_MEMORY_SCOPE_AGENT);
                jn = idx[(size_t)p * KSEL + lane];
            }
            float mx = a;
#pragma unroll
            for (int o = 32; o > 0; o >>= 1) mx = fmaxf(mx, __shfl_xor(mx, o, 64));
            const float e = (lane < KSEL) ? expf(a - mx) : 0.0f;
            float se = e;
#pragma unroll
            for (int o = 32; o > 0; o >>= 1) se += __shfl_xor(se, o, 64);
            const float w = e / se;

            float accv = 0.0f;
            for (int t = 0; t < KSEL; ++t) {
                const int   jt = __shfl(jn, t, 64);
                const float wt = __shfl(w, t, 64);
                accv = fmaf(wt, xTb[((size_t)jt << 6) + lane], accv);
            }
            agg[pl][lane] = accv;
        }
        __syncthreads();

        const float* xb = x + ((size_t)b << 18);
        float* ob = out + ((size_t)b << 18);
        const int nl = tid & 31, cb = tid >> 5;
#pragma unroll
        for (int i = 0; i < 8; ++i) {
            const int c = (i << 3) + cb;
            const size_t off = ((size_t)c << 12) + n0 + nl;
            ob[off] = xb[off] + agg[nl][c];
        }
    }
}

// ---------------------------------------------------------------------------
extern "C" void kernel_launch(void* const* d_in, const int* in_sizes, int n_in,
                              void* d_out, int out_size, void* d_ws, size_t ws_size,
                              hipStream_t stream) {
    const float* x_loc = (const float*)d_in[0];
    const float* x     = (const float*)d_in[1];
    const float* W1    = (const float*)d_in[2];
    const float* g1    = (const float*)d_in[3];
    const float* b1    = (const float*)d_in[4];
    const float* W2    = (const float*)d_in[5];
    const float* g2    = (const float*)d_in[6];
    const float* b2    = (const float*)d_in[7];
    const float* W3    = (const float*)d_in[8];
    const float* g3    = (const float*)d_in[9];
    const float* b3    = (const float*)d_in[10];
    float* out = (float*)d_out;

    char* ws = (char*)d_ws;
    unsigned* bar = (unsigned*)ws;                   // 16 uints
    float* accM = (float*)(ws + 64);                 // 9*64
    float* acc2 = (float*)(ws + 2368);               // 27*64
    float* acc3 = (float*)(ws + 9280);               // 9*64
    float* sph  = (float*)(ws + 12288);              // 3*NROWS
    float* att  = sph + 3 * (size_t)NROWS;           // NROWS
    int*   idx  = (int*)(att + NROWS);               // NROWS
    float* xT   = (float*)(idx + NROWS);             // B*N*C

    hipMemsetAsync(ws, 0, 12288, stream);

    knn_k<<<dim3(NPTS / 8, NB), 512, 0, stream>>>(x_loc, idx, sph, accM);
    transpose_k<<<dim3(NPTS / 64, NB), 256, 0, stream>>>(x, xT);
    coop_k<<<NBLK, 256, 0, stream>>>(x, W1, g1, b1, W2, g2, b2, W3, g3, b3,
                                     sph, att, idx, xT, accM, acc2, acc3, bar, out);
}

// Round 4
// 358.639 us; speedup vs baseline: 1.8059x; 1.8059x over previous
//
#include <hip/hip_runtime.h>
#include <math.h>

#define NPTS 4096
#define NB   8
#define NC   64
#define KSEL 30
#define NROWS (NB * NPTS * KSEL)   // 983040
#define CNT_F 983040.0f

static __device__ __forceinline__ unsigned long long shfl_xor_u64(unsigned long long v, int lx) {
    int lo = __shfl_xor((int)(unsigned)(v & 0xFFFFFFFFULL), lx, 64);
    int hi = __shfl_xor((int)(unsigned)(v >> 32), lx, 64);
    return ((unsigned long long)(unsigned)hi << 32) | (unsigned)lo;
}

// ---------------------------------------------------------------------------
// helpers: per-block reduction of 64-spread accumulator slots, BN param math
// ---------------------------------------------------------------------------
template <int NM>
static __device__ __forceinline__ void slot_reduce(const float* __restrict__ acc,
                                                   float* __restrict__ sSum, int tid) {
    if (tid < 64) {
        float pm[NM];
#pragma unroll
        for (int m = 0; m < NM; ++m) pm[m] = acc[m * 64 + tid];
#pragma unroll
        for (int o = 32; o > 0; o >>= 1) {
#pragma unroll
            for (int m = 0; m < NM; ++m) pm[m] += __shfl_xor(pm[m], o, 64);
        }
        if (tid == 0) {
#pragma unroll
            for (int m = 0; m < NM; ++m) sSum[m] = pm[m];
        }
    }
}

// BN1 params from sph moments (y1 = W1 @ [sph; sph-mean] is linear in sph)
static __device__ __forceinline__ void bn1_params(const float* __restrict__ sSum,
                                                  const float* __restrict__ W1,
                                                  const float* __restrict__ g1,
                                                  const float* __restrict__ b1,
                                                  float* __restrict__ sPar, int tid) {
    if (tid < 6) {
        const float invN = 1.0f / CNT_F;
        const float m0 = sSum[0] * invN, m1 = sSum[1] * invN, m2 = sSum[2] * invN;
        const float E00 = sSum[3] * invN, E01 = sSum[4] * invN, E02 = sSum[5] * invN;
        const float E11 = sSum[6] * invN, E12 = sSum[7] * invN, E22 = sSum[8] * invN;
        const float* w = W1 + tid * 6;
        const float third = (w[3] + w[4] + w[5]) * (1.0f / 3.0f);
        const float a0 = w[0] + w[3] - third;
        const float a1 = w[1] + w[4] - third;
        const float a2 = w[2] + w[5] - third;
        const float mu = a0 * m0 + a1 * m1 + a2 * m2;
        const float E2 = a0 * a0 * E00 + a1 * a1 * E11 + a2 * a2 * E22 +
                         2.0f * (a0 * a1 * E01 + a0 * a2 * E02 + a1 * a2 * E12);
        const float var = E2 - mu * mu;
        const float sc = g1[tid] / sqrtf(var + 1e-5f);
        sPar[tid] = sc;
        sPar[6 + tid] = b1[tid] - mu * sc;
    }
}

static __device__ __forceinline__ void bn2_params(const float* __restrict__ sSum,
                                                  const float* __restrict__ W2,
                                                  const float* __restrict__ g2,
                                                  const float* __restrict__ b2,
                                                  float* __restrict__ sPar, int tid) {
    if (tid < 3) {
        const float invN = 1.0f / CNT_F;
        float Eh[6];
#pragma unroll
        for (int d = 0; d < 6; ++d) Eh[d] = sSum[d] * invN;
        float M[6][6];
        int q = 6;
#pragma unroll
        for (int a2 = 0; a2 < 6; ++a2)
#pragma unroll
            for (int b2_ = a2; b2_ < 6; ++b2_) {
                const float v = sSum[q++] * invN;
                M[a2][b2_] = v; M[b2_][a2] = v;
            }
        const float* w = W2 + tid * 6;
        float mu = 0.0f;
#pragma unroll
        for (int d = 0; d < 6; ++d) mu += w[d] * Eh[d];
        float E2 = 0.0f;
#pragma unroll
        for (int a2 = 0; a2 < 6; ++a2)
#pragma unroll
            for (int b2_ = 0; b2_ < 6; ++b2_) E2 += w[a2] * w[b2_] * M[a2][b2_];
        const float var = E2 - mu * mu;
        const float sc = g2[tid] / sqrtf(var + 1e-5f);
        sPar[12 + tid] = sc;
        sPar[15 + tid] = b2[tid] - mu * sc;
    }
}

static __device__ __forceinline__ void bn3_params(const float* __restrict__ sSum,
                                                  const float* __restrict__ W3,
                                                  const float* __restrict__ g3,
                                                  const float* __restrict__ b3,
                                                  float* __restrict__ sPar, int tid) {
    if (tid == 0) {
        const float invN = 1.0f / CNT_F;
        const float Eh0 = sSum[0] * invN, Eh1 = sSum[1] * invN, Eh2 = sSum[2] * invN;
        const float M00 = sSum[3] * invN, M01 = sSum[4] * invN, M02 = sSum[5] * invN;
        const float M11 = sSum[6] * invN, M12 = sSum[7] * invN, M22 = sSum[8] * invN;
        const float w0 = W3[0], w1 = W3[1], w2 = W3[2];
        const float mu = w0 * Eh0 + w1 * Eh1 + w2 * Eh2;
        const float E2 = w0 * w0 * M00 + w1 * w1 * M11 + w2 * w2 * M22 +
                         2.0f * (w0 * w1 * M01 + w0 * w2 * M02 + w1 * w2 * M12);
        const float var = E2 - mu * mu;
        const float sc = g3[0] / sqrtf(var + 1e-5f);
        sPar[18] = sc;
        sPar[19] = b3[0] - mu * sc;
    }
}

static __device__ __forceinline__ void mlp_h1(float s0, float s1, float s2,
                                              const float* __restrict__ W1,
                                              const float* __restrict__ sPar,
                                              float* __restrict__ h1) {
    const float mean = (s0 + s1 + s2) * (1.0f / 3.0f);
    const float f[6] = {s0, s1, s2, s0 - mean, s1 - mean, s2 - mean};
#pragma unroll
    for (int c = 0; c < 6; ++c) {
        float a = 0.0f;
#pragma unroll
        for (int d = 0; d < 6; ++d) a = fmaf(W1[c * 6 + d], f[d], a);
        const float z = fmaf(a, sPar[c], sPar[6 + c]);
        h1[c] = z >= 0.0f ? z : 0.2f * z;
    }
}

static __device__ __forceinline__ void mlp_h2(const float* __restrict__ h1,
                                              const float* __restrict__ W2,
                                              const float* __restrict__ sPar,
                                              float* __restrict__ h2) {
#pragma unroll
    for (int c = 0; c < 3; ++c) {
        float a = 0.0f;
#pragma unroll
        for (int d = 0; d < 6; ++d) a = fmaf(W2[c * 6 + d], h1[d], a);
        const float z = fmaf(a, sPar[12 + c], sPar[15 + c]);
        h2[c] = z >= 0.0f ? z : 0.2f * z;
    }
}

// ---------------------------------------------------------------------------
// Kernel 1: exact KNN + spherical features + BN1 sufficient statistics.
// 8 queries/block (one per wave). LDS: xyz 48KB + {xx-plane | survivors} 16KB.
// ---------------------------------------------------------------------------
__global__ __launch_bounds__(512, 4) void knn_k(const float* __restrict__ xloc,
                                                int* __restrict__ idx_out,
                                                float* __restrict__ sph,   // [3][NROWS]
                                                float* __restrict__ accM) {
    __shared__ float s3[NPTS * 3];
    __shared__ float swu[NPTS];

    const int tid  = threadIdx.x;
    const int lane = tid & 63;
    const int wv   = tid >> 6;
    const int b    = blockIdx.y;
    const int n    = (blockIdx.x << 3) + wv;

    const float* xb = xloc + (size_t)b * (3 * NPTS);
    for (int i = tid; i < NPTS; i += 512) {
        const float x = xb[i], y = xb[NPTS + i], z = xb[2 * NPTS + i];
        s3[i * 3]     = x;
        s3[i * 3 + 1] = y;
        s3[i * 3 + 2] = z;
        swu[i] = __fadd_rn(__fadd_rn(__fmul_rn(x, x), __fmul_rn(y, y)), __fmul_rn(z, z));
    }
    __syncthreads();

    const float qx = s3[n * 3], qy = s3[n * 3 + 1], qz = s3[n * 3 + 2];
    const float qw = swu[n];

    float P[64];
    float pmax = -3.4e38f;
#pragma unroll
    for (int t = 0; t < 64; ++t) {
        const int j = lane + (t << 6);
        const float cx = s3[j * 3], cy = s3[j * 3 + 1], cz = s3[j * 3 + 2];
        const float cw = swu[j];
        const float dt = __fadd_rn(__fadd_rn(__fmul_rn(qx, cx), __fmul_rn(qy, cy)), __fmul_rn(qz, cz));
        const float pd = __fsub_rn(__fsub_rn(__fadd_rn(dt, dt), qw), cw);
        P[t] = pd;
        pmax = fmaxf(pmax, pd);
    }

    float v = pmax;
#pragma unroll
    for (int k = 2; k <= 64; k <<= 1) {
#pragma unroll
        for (int j2 = k >> 1; j2 > 0; j2 >>= 1) {
            const float o = __shfl_xor(v, j2, 64);
            const bool keepmax = ((lane & j2) == 0) == ((lane & k) == 0);
            v = keepmax ? fmaxf(v, o) : fminf(v, o);
        }
    }
    const float tau = __shfl(v, 30, 64);

    __syncthreads();

    unsigned long long* surv = ((unsigned long long*)swu) + (wv << 6);
    surv[lane] = 0ULL;

    unsigned total = 0;
#pragma unroll
    for (int t = 0; t < 64; ++t) {
        const bool p = (P[t] >= tau);
        const unsigned long long m = __ballot(p);
        if (p) {
            const unsigned pos = total + (unsigned)__popcll(m & ((1ULL << lane) - 1ULL));
            if (pos < 64u) {
                const unsigned u = __float_as_uint(P[t]);
                const unsigned key = u ^ ((unsigned)((int)u >> 31) | 0x80000000u);
                surv[pos] = ((unsigned long long)key << 32) | (unsigned)(~(lane + (t << 6)));
            }
        }
        total += (unsigned)__popcll(m);
    }
    __threadfence_block();

    const int bn = (b << 12) + n;
    const size_t obase = (size_t)bn * KSEL;
    int jn = 0;

    if (total <= 64u) {
        unsigned long long s = surv[lane];
#pragma unroll
        for (int k = 2; k <= 64; k <<= 1) {
#pragma unroll
            for (int j2 = k >> 1; j2 > 0; j2 >>= 1) {
                const unsigned long long o = shfl_xor_u64(s, j2);
                const bool keepmax = ((lane & j2) == 0) == ((lane & k) == 0);
                const unsigned long long mx = s > o ? s : o;
                const unsigned long long mn = s > o ? o : s;
                s = keepmax ? mx : mn;
            }
        }
        jn = (int)(~(unsigned)s) & (NPTS - 1);
        if (lane >= KSEL) jn = 0;
    } else {
        auto keyf = [&](int j) -> unsigned {
            const float cx = s3[j * 3], cy = s3[j * 3 + 1], cz = s3[j * 3 + 2];
            const float cw = __fadd_rn(__fadd_rn(__fmul_rn(cx, cx), __fmul_rn(cy, cy)), __fmul_rn(cz, cz));
            const float dt = __fadd_rn(__fadd_rn(__fmul_rn(qx, cx), __fmul_rn(qy, cy)), __fmul_rn(qz, cz));
            const float pd = __fsub_rn(__fsub_rn(__fadd_rn(dt, dt), qw), cw);
            const unsigned u = __float_as_uint(pd);
            return u ^ ((unsigned)((int)u >> 31) | 0x80000000u);
        };
        unsigned Pv = 0;
        for (int bit = 31; bit >= 0; --bit) {
            const unsigned cand = Pv | (1u << bit);
            int c = 0;
            for (int t = 0; t < 64; ++t) c += (keyf(lane + (t << 6)) >= cand) ? 1 : 0;
            for (int o = 32; o > 0; o >>= 1) c += __shfl_xor(c, o, 64);
            if (c >= KSEL) Pv = cand;
        }
        int* sj = (int*)surv;
        int emitted = 0;
        for (int t = 0; t < 64; ++t) {
            const bool g = keyf(lane + (t << 6)) > Pv;
            const unsigned long long m = __ballot(g);
            if (g) {
                const int pos = emitted + (int)__popcll(m & ((1ULL << lane) - 1ULL));
                if (pos < KSEL) sj[pos] = lane + (t << 6);
            }
            emitted += (int)__popcll(m);
        }
        for (int t = 0; t < 64; ++t) {
            const bool e_ = (keyf(lane + (t << 6)) == Pv);
            const unsigned long long m = __ballot(e_);
            const int before = (int)__popcll(m & ((1ULL << lane) - 1ULL));
            if (e_ && (emitted + before) < KSEL) sj[emitted + before] = lane + (t << 6);
            emitted += (int)__popcll(m);
        }
        __threadfence_block();
        if (lane < KSEL) jn = sj[lane];
    }

    float s0 = 0.0f, s1 = 0.0f, s2 = 0.0f;
    if (lane < KSEL) {
        idx_out[obase + lane] = jn;
        const float cx = s3[jn * 3], cy = s3[jn * 3 + 1], cz = s3[jn * 3 + 2];
        const float xr = cx - qx, yr = cy - qy, zr = cz - qz;
        const float sxy2 = xr * xr + yr * yr;
        const float r2   = sxy2 + zr * zr;
        const float rho  = sqrtf(fmaxf(r2, 1e-20f));
        const float sxy  = sqrtf(fmaxf(sxy2, 1e-20f));
        const bool dr = r2 < 1e-20f;
        const bool dp = sxy2 < 1e-20f;
        const float theta = atan2f(dr ? 0.0f : zr, dr ? 1.0f : sxy);
        const float phi   = atan2f(dp ? 0.0f : yr, dp ? 1.0f : xr);
        sph[obase + lane]             = rho;
        sph[NROWS + obase + lane]     = theta;
        sph[2 * NROWS + obase + lane] = phi;
        s0 = rho; s1 = theta; s2 = phi;
    }

    float mom[9] = {s0, s1, s2, s0 * s0, s0 * s1, s0 * s2, s1 * s1, s1 * s2, s2 * s2};
#pragma unroll
    for (int o = 32; o > 0; o >>= 1) {
#pragma unroll
        for (int m = 0; m < 9; ++m) mom[m] += __shfl_xor(mom[m], o, 64);
    }
    float* msc = swu + 1024;
    if (lane == 0) {
#pragma unroll
        for (int m = 0; m < 9; ++m) msc[wv * 9 + m] = mom[m];
    }
    __syncthreads();
    if (tid < 9) {
        float t_ = 0.0f;
#pragma unroll
        for (int w = 0; w < 8; ++w) t_ += msc[w * 9 + tid];
        atomicAdd(&accM[tid * 64 + ((blockIdx.y * (NPTS / 8) + blockIdx.x) & 63)], t_);
    }
}

// ---------------------------------------------------------------------------
// Kernel 2: tiled transpose x [B,C,N] -> xT [B,N,C]
// ---------------------------------------------------------------------------
__global__ __launch_bounds__(256) void transpose_k(const float* __restrict__ x,
                                                   float* __restrict__ xT) {
    __shared__ float tile[64][65];
    const int b  = blockIdx.y;
    const int n0 = blockIdx.x << 6;
    const int tx = threadIdx.x & 63;
    const int ty = threadIdx.x >> 6;
    const float* xb = x + ((size_t)b << 18);
#pragma unroll
    for (int i = 0; i < 16; ++i) {
        const int c = (i << 2) + ty;
        tile[c][tx] = xb[((size_t)c << 12) + n0 + tx];
    }
    __syncthreads();
    float* ob = xT + ((size_t)b << 18);
#pragma unroll
    for (int i = 0; i < 16; ++i) {
        const int nl = (i << 2) + ty;
        ob[((size_t)(n0 + nl) << 6) + tx] = tile[tx][nl];
    }
}

// ---------------------------------------------------------------------------
// Kernel 3: h1 moments (27) from sph; BN1 params derived per block.
// ---------------------------------------------------------------------------
__global__ __launch_bounds__(256) void p2_k(const float* __restrict__ sph,
                                            const float* __restrict__ W1,
                                            const float* __restrict__ g1,
                                            const float* __restrict__ b1,
                                            const float* __restrict__ accM,
                                            float* __restrict__ acc2) {
    __shared__ float sSum[9];
    __shared__ float sPar[12];
    __shared__ float red[4][27];
    const int tid = threadIdx.x;
    slot_reduce<9>(accM, sSum, tid);
    __syncthreads();
    bn1_params(sSum, W1, g1, b1, sPar, tid);
    __syncthreads();

    const size_t r = (size_t)blockIdx.x * 256 + tid;
    const float s0 = sph[r], s1 = sph[NROWS + r], s2 = sph[2 * NROWS + r];
    float h1[6];
    mlp_h1(s0, s1, s2, W1, sPar, h1);

    float m27[27];
    int q = 6;
#pragma unroll
    for (int a2 = 0; a2 < 6; ++a2) {
        m27[a2] = h1[a2];
#pragma unroll
        for (int b2_ = a2; b2_ < 6; ++b2_) m27[q++] = h1[a2] * h1[b2_];
    }
#pragma unroll
    for (int o = 32; o > 0; o >>= 1) {
#pragma unroll
        for (int m = 0; m < 27; ++m) m27[m] += __shfl_xor(m27[m], o, 64);
    }
    const int lane = tid & 63, wv = tid >> 6;
    if (lane == 0) {
#pragma unroll
        for (int m = 0; m < 27; ++m) red[wv][m] = m27[m];
    }
    __syncthreads();
    if (tid < 27) {
        const float v = red[0][tid] + red[1][tid] + red[2][tid] + red[3][tid];
        atomicAdd(&acc2[tid * 64 + (blockIdx.x & 63)], v);
    }
}

// ---------------------------------------------------------------------------
// Kernel 4: h2 moments (9) from sph; BN1+BN2 params derived per block.
// ---------------------------------------------------------------------------
__global__ __launch_bounds__(256) void p3_k(const float* __restrict__ sph,
                                            const float* __restrict__ W1,
                                            const float* __restrict__ g1,
                                            const float* __restrict__ b1,
                                            const float* __restrict__ W2,
                                            const float* __restrict__ g2,
                                            const float* __restrict__ b2,
                                            const float* __restrict__ accM,
                                            const float* __restrict__ acc2,
                                            float* __restrict__ acc3) {
    __shared__ float sSum[27];
    __shared__ float sPar[18];
    __shared__ float red[4][9];
    const int tid = threadIdx.x;
    slot_reduce<9>(accM, sSum, tid);
    __syncthreads();
    bn1_params(sSum, W1, g1, b1, sPar, tid);
    __syncthreads();
    slot_reduce<27>(acc2, sSum, tid);
    __syncthreads();
    bn2_params(sSum, W2, g2, b2, sPar, tid);
    __syncthreads();

    const size_t r = (size_t)blockIdx.x * 256 + tid;
    const float s0 = sph[r], s1 = sph[NROWS + r], s2 = sph[2 * NROWS + r];
    float h1[6], h2[3];
    mlp_h1(s0, s1, s2, W1, sPar, h1);
    mlp_h2(h1, W2, sPar, h2);

    float m9[9] = {h2[0], h2[1], h2[2],
                   h2[0] * h2[0], h2[0] * h2[1], h2[0] * h2[2],
                   h2[1] * h2[1], h2[1] * h2[2], h2[2] * h2[2]};
#pragma unroll
    for (int o = 32; o > 0; o >>= 1) {
#pragma unroll
        for (int m = 0; m < 9; ++m) m9[m] += __shfl_xor(m9[m], o, 64);
    }
    const int lane = tid & 63, wv = tid >> 6;
    if (lane == 0) {
#pragma unroll
        for (int m = 0; m < 9; ++m) red[wv][m] = m9[m];
    }
    __syncthreads();
    if (tid < 9) {
        const float v = red[0][tid] + red[1][tid] + red[2][tid] + red[3][tid];
        atomicAdd(&acc3[tid * 64 + (blockIdx.x & 63)], v);
    }
}

// ---------------------------------------------------------------------------
// Kernel 5: full MLP recompute -> att, softmax over k, gather, residual out.
// 32 points per block (8 per wave); LDS-tiled coalesced output stores.
// ---------------------------------------------------------------------------
__global__ __launch_bounds__(256) void p4_k(const float* __restrict__ sph,
                                            const int* __restrict__ idx,
                                            const float* __restrict__ x,
                                            const float* __restrict__ xT,
                                            const float* __restrict__ W1,
                                            const float* __restrict__ g1,
                                            const float* __restrict__ b1,
                                            const float* __restrict__ W2,
                                            const float* __restrict__ g2,
                                            const float* __restrict__ b2,
                                            const float* __restrict__ W3,
                                            const float* __restrict__ g3,
                                            const float* __restrict__ b3,
                                            const float* __restrict__ accM,
                                            const float* __restrict__ acc2,
                                            const float* __restrict__ acc3,
                                            float* __restrict__ out) {
    __shared__ float sSum[27];
    __shared__ float sPar[20];
    __shared__ float agg[32][65];
    const int tid = threadIdx.x;
    slot_reduce<9>(accM, sSum, tid);
    __syncthreads();
    bn1_params(sSum, W1, g1, b1, sPar, tid);
    __syncthreads();
    slot_reduce<27>(acc2, sSum, tid);
    __syncthreads();
    bn2_params(sSum, W2, g2, b2, sPar, tid);
    __syncthreads();
    slot_reduce<9>(acc3, sSum, tid);
    __syncthreads();
    bn3_params(sSum, W3, g3, b3, sPar, tid);
    __syncthreads();

    const int lane = tid & 63, wv = tid >> 6;
    const int p0 = blockIdx.x << 5;          // 32 consecutive points
    const int b  = p0 >> 12;
    const int n0 = p0 & (NPTS - 1);
    const float* xTb = xT + ((size_t)b << 18);

    for (int i = 0; i < 8; ++i) {
        const int pl = (wv << 3) + i;
        const int p  = p0 + pl;
        float a = -3.4e38f;
        int jn = 0;
        if (lane < KSEL) {
            const size_t r = (size_t)p * KSEL + lane;
            const float s0 = sph[r], s1 = sph[NROWS + r], s2 = sph[2 * NROWS + r];
            float h1[6], h2[3];
            mlp_h1(s0, s1, s2, W1, sPar, h1);
            mlp_h2(h1, W2, sPar, h2);
            float y = 0.0f;
#pragma unroll
            for (int d = 0; d < 3; ++d) y = fmaf(W3[d], h2[d], y);
            const float z = fmaf(y, sPar[18], sPar[19]);
            a = z >= 0.0f ? z : 0.2f * z;
            jn = idx[r];
        }
        float mx = a;
#pragma unroll
        for (int o = 32; o > 0; o >>= 1) mx = fmaxf(mx, __shfl_xor(mx, o, 64));
        const float e = (lane < KSEL) ? expf(a - mx) : 0.0f;
        float se = e;
#pragma unroll
        for (int o = 32; o > 0; o >>= 1) se += __shfl_xor(se, o, 64);
        const float w = e / se;

        float acc0 = 0.0f, acc1 = 0.0f;
#pragma unroll
        for (int t = 0; t < KSEL; t += 2) {
            const int   j0 = __shfl(jn, t, 64);
            const float w0 = __shfl(w, t, 64);
            const int   j1 = __shfl(jn, t + 1, 64);
            const float w1 = __shfl(w, t + 1, 64);
            acc0 = fmaf(w0, xTb[((size_t)j0 << 6) + lane], acc0);
            acc1 = fmaf(w1, xTb[((size_t)j1 << 6) + lane], acc1);
        }
        agg[pl][lane] = acc0 + acc1;
    }
    __syncthreads();

    const float* xb = x + ((size_t)b << 18);
    float* ob = out + ((size_t)b << 18);
    const int nl = tid & 31, cb = tid >> 5;
#pragma unroll
    for (int i = 0; i < 8; ++i) {
        const int c = (i << 3) + cb;
        const size_t off = ((size_t)c << 12) + n0 + nl;
        ob[off] = xb[off] + agg[nl][c];
    }
}

// ---------------------------------------------------------------------------
extern "C" void kernel_launch(void* const* d_in, const int* in_sizes, int n_in,
                              void* d_out, int out_size, void* d_ws, size_t ws_size,
                              hipStream_t stream) {
    const float* x_loc = (const float*)d_in[0];
    const float* x     = (const float*)d_in[1];
    const float* W1    = (const float*)d_in[2];
    const float* g1    = (const float*)d_in[3];
    const float* b1    = (const float*)d_in[4];
    const float* W2    = (const float*)d_in[5];
    const float* g2    = (const float*)d_in[6];
    const float* b2    = (const float*)d_in[7];
    const float* W3    = (const float*)d_in[8];
    const float* g3    = (const float*)d_in[9];
    const float* b3    = (const float*)d_in[10];
    float* out = (float*)d_out;

    float* accM = (float*)d_ws;                 //  9*64
    float* acc2 = accM + 576;                   // 27*64
    float* acc3 = acc2 + 1728;                  //  9*64
    float* sph  = acc3 + 576;                   // 3*NROWS
    int*   idx  = (int*)(sph + 3 * (size_t)NROWS);
    float* xT   = (float*)(idx + NROWS);        // B*N*C

    hipMemsetAsync(d_ws, 0, 11520, stream);

    knn_k<<<dim3(NPTS / 8, NB), 512, 0, stream>>>(x_loc, idx, sph, accM);
    transpose_k<<<dim3(NPTS / 64, NB), 256, 0, stream>>>(x, xT);
    p2_k<<<NROWS / 256, 256, 0, stream>>>(sph, W1, g1, b1, accM, acc2);
    p3_k<<<NROWS / 256, 256, 0, stream>>>(sph, W1, g1, b1, W2, g2, b2, accM, acc2, acc3);
    p4_k<<<(NB * NPTS) / 32, 256, 0, stream>>>(sph, idx, x, xT, W1, g1, b1, W2, g2, b2,
                                               W3, g3, b3, accM, acc2, acc3, out);
}